// Round 2
// baseline (586.484 us; speedup 1.0000x reference)
//
#include <hip/hip_runtime.h>
#include <math.h>

#define NF 8192

// ---------- complex helpers ----------
__device__ __forceinline__ int phys(int e) { return e ^ (((e >> 4) & 7) << 1); }

__device__ __forceinline__ float2 cmul(float2 a, float2 b) {
    return make_float2(a.x*b.x - a.y*b.y, a.x*b.y + a.y*b.x);
}
__device__ __forceinline__ float2 cmulc(float2 a, float2 b) { // a * conj(b)
    return make_float2(a.x*b.x + a.y*b.y, a.y*b.x - a.x*b.y);
}
__device__ __forceinline__ float2 cadd(float2 a, float2 b){ return make_float2(a.x+b.x, a.y+b.y); }
__device__ __forceinline__ float2 csub(float2 a, float2 b){ return make_float2(a.x-b.x, a.y-b.y); }
__device__ __forceinline__ float2 mnegi(float2 a){ return make_float2(a.y, -a.x); }   // * (-i)
__device__ __forceinline__ float2 mposi(float2 a){ return make_float2(-a.y, a.x); }   // * (+i)
#define RSQ2 0.70710678118654752f
__device__ __forceinline__ float2 mw81 (float2 a){ return make_float2( RSQ2*(a.x+a.y),  RSQ2*(a.y-a.x)); } // * e^{-i pi/4}
__device__ __forceinline__ float2 mw83 (float2 a){ return make_float2( RSQ2*(a.y-a.x), -RSQ2*(a.x+a.y)); } // * e^{-3i pi/4}
__device__ __forceinline__ float2 mw81c(float2 a){ return make_float2( RSQ2*(a.x-a.y),  RSQ2*(a.x+a.y)); } // * e^{+i pi/4}
__device__ __forceinline__ float2 mw83c(float2 a){ return make_float2(-RSQ2*(a.x+a.y),  RSQ2*(a.x-a.y)); } // * e^{+3i pi/4}

// w16 constants
#define C16_1 0.92387953251128674f
#define S16_1 0.38268343236508978f
#define C16_2 0.70710678118654752f

// DIF radix-8 core. After: y0=v0 y1=v4 y2=v2 y3=v6 y4=v1 y5=v5 y6=v3 y7=v7
__device__ __forceinline__ void dif8_core(float2& v0, float2& v1, float2& v2, float2& v3,
                                          float2& v4, float2& v5, float2& v6, float2& v7) {
    float2 t;
    t = csub(v0, v4); v0 = cadd(v0, v4); v4 = t;
    t = csub(v1, v5); v1 = cadd(v1, v5); v5 = mw81(t);
    t = csub(v2, v6); v2 = cadd(v2, v6); v6 = mnegi(t);
    t = csub(v3, v7); v3 = cadd(v3, v7); v7 = mw83(t);
    t = csub(v0, v2); v0 = cadd(v0, v2); v2 = t;
    t = csub(v1, v3); v1 = cadd(v1, v3); v3 = mnegi(t);
    t = csub(v4, v6); v4 = cadd(v4, v6); v6 = t;
    t = csub(v5, v7); v5 = cadd(v5, v7); v7 = mnegi(t);
    t = csub(v0, v1); v0 = cadd(v0, v1); v1 = t;
    t = csub(v2, v3); v2 = cadd(v2, v3); v3 = t;
    t = csub(v4, v5); v4 = cadd(v4, v5); v5 = t;
    t = csub(v6, v7); v6 = cadd(v6, v7); v7 = t;
}

// DIT radix-8 core. Inputs v0=y0 v1=y4*c4 v2=y2*c2 v3=y6*c6 v4=y1*c1 v5=y5*c5 v6=y3*c3 v7=y7*c7
// Outputs x0..x7 in v0..v7.
__device__ __forceinline__ void dit8_core(float2& v0, float2& v1, float2& v2, float2& v3,
                                          float2& v4, float2& v5, float2& v6, float2& v7) {
    float2 t;
    t = csub(v0, v1); v0 = cadd(v0, v1); v1 = t;
    t = csub(v2, v3); v2 = cadd(v2, v3); v3 = t;
    t = csub(v4, v5); v4 = cadd(v4, v5); v5 = t;
    t = csub(v6, v7); v6 = cadd(v6, v7); v7 = t;
    t = v2;        v2 = csub(v0, t); v0 = cadd(v0, t);
    t = mposi(v3); v3 = csub(v1, t); v1 = cadd(v1, t);
    t = v6;        v6 = csub(v4, t); v4 = cadd(v4, t);
    t = mposi(v7); v7 = csub(v5, t); v5 = cadd(v5, t);
    t = v4;        v4 = csub(v0, t); v0 = cadd(v0, t);
    t = mw81c(v5); v5 = csub(v1, t); v1 = cadd(v1, t);
    t = mposi(v6); v6 = csub(v2, t); v2 = cadd(v2, t);
    t = mw83c(v7); v7 = csub(v3, t); v3 = cadd(v3, t);
}

// ---------- radix-8 LDS passes (512 threads) ----------
template<int M, int LM>
__device__ __forceinline__ void fwd8_lds(float2* Z, const float2* __restrict__ tw, int tid) {
    #pragma unroll
    for (int q = 0; q < 2; ++q) {
        int beta = tid + q*512;
        int i    = beta & (M-1);
        int base = ((beta >> LM) << (LM+3)) + i;
        float2 v0 = Z[phys(base        )];
        float2 v1 = Z[phys(base + 1*M)];
        float2 v2 = Z[phys(base + 2*M)];
        float2 v3 = Z[phys(base + 3*M)];
        float2 v4 = Z[phys(base + 4*M)];
        float2 v5 = Z[phys(base + 5*M)];
        float2 v6 = Z[phys(base + 6*M)];
        float2 v7 = Z[phys(base + 7*M)];
        dif8_core(v0,v1,v2,v3,v4,v5,v6,v7);
        int ts = (NF >> (LM+3)) * i;
        Z[phys(base        )] = v0;
        Z[phys(base + 4*M)] = cmul(v1, tw[ts*4]);
        Z[phys(base + 2*M)] = cmul(v2, tw[ts*2]);
        Z[phys(base + 6*M)] = cmul(v3, tw[ts*6]);
        Z[phys(base + 1*M)] = cmul(v4, tw[ts  ]);
        Z[phys(base + 5*M)] = cmul(v5, tw[ts*5]);
        Z[phys(base + 3*M)] = cmul(v6, tw[ts*3]);
        Z[phys(base + 7*M)] = cmul(v7, tw[ts*7]);
    }
}

template<int M, int LM>
__device__ __forceinline__ void inv8_lds(float2* Z, const float2* __restrict__ tw, int tid) {
    #pragma unroll
    for (int q = 0; q < 2; ++q) {
        int beta = tid + q*512;
        int i    = beta & (M-1);
        int base = ((beta >> LM) << (LM+3)) + i;
        int ts   = (NF >> (LM+3)) * i;
        float2 v0 = Z[phys(base        )];
        float2 v1 = cmulc(Z[phys(base + 4*M)], tw[ts*4]);
        float2 v2 = cmulc(Z[phys(base + 2*M)], tw[ts*2]);
        float2 v3 = cmulc(Z[phys(base + 6*M)], tw[ts*6]);
        float2 v4 = cmulc(Z[phys(base + 1*M)], tw[ts  ]);
        float2 v5 = cmulc(Z[phys(base + 5*M)], tw[ts*5]);
        float2 v6 = cmulc(Z[phys(base + 3*M)], tw[ts*3]);
        float2 v7 = cmulc(Z[phys(base + 7*M)], tw[ts*7]);
        dit8_core(v0,v1,v2,v3,v4,v5,v6,v7);
        Z[phys(base        )] = v0;
        Z[phys(base + 1*M)] = v1;
        Z[phys(base + 2*M)] = v2;
        Z[phys(base + 3*M)] = v3;
        Z[phys(base + 4*M)] = v4;
        Z[phys(base + 5*M)] = v5;
        Z[phys(base + 6*M)] = v6;
        Z[phys(base + 7*M)] = v7;
    }
}

// ---------- kernels ----------
__global__ void twiddle_kernel(float2* __restrict__ tw) {
    int j = blockIdx.x * 256 + threadIdx.x;
    double ang = -6.283185307179586476925286766559 * (double)j / 8192.0;
    tw[j] = make_float2((float)cos(ang), (float)sin(ang));
}

// Position-MLP: a[c][e] = decay(e) * rpe(offset(e))[c].  2048 blocks x 4 waves, 1 pos/wave.
__global__ __launch_bounds__(256) void rpe_kernel(
    const float* __restrict__ pw,  const float* __restrict__ pb,
    const float* __restrict__ lws, const float* __restrict__ lbs,
    const float* __restrict__ ow,  const float* __restrict__ ob,
    float* __restrict__ a_buf)
{
    __shared__ float sW[3][64][64];     // 48 KB (sW[0] reused as out_w chunk later)
    __shared__ float sB[3][64];
    __shared__ float sPW[64], sPB[64];
    __shared__ float sAct[4][64];
    int tid = threadIdx.x;
    for (int idx = tid; idx < 3*64*64; idx += 256) ((float*)sW)[idx] = lws[idx];
    if (tid < 3*64) ((float*)sB)[tid] = lbs[tid];
    if (tid < 64) { sPW[tid] = pw[tid]; sPB[tid] = pb[tid]; }
    __syncthreads();

    int wave = tid >> 6, lane = tid & 63;
    int e = blockIdx.x * 4 + wave;
    float p = (e == 4096) ? 0.f : ((e < 4096) ? (float)e : (float)(e - 8192));
    int m = (e < 4096) ? e : (8192 - e);
    if (e == 4096) m = 0;
    float dec = exp2f(-0.0014434309482562475f * (float)m);   // log2(0.999)

    float xv = fmaf(p, sPW[lane], sPB[lane]);
    for (int L = 0; L < 3; ++L) {
        float ss = xv * xv;
        #pragma unroll
        for (int o = 1; o < 64; o <<= 1) ss += __shfl_xor(ss, o);
        float act = fmaxf(xv / (sqrtf(ss) * 0.125f + 1e-8f), 0.f);
        sAct[wave][lane] = act;
        __syncthreads();
        float y0 = sB[L][lane], y1 = 0.f;
        #pragma unroll
        for (int k = 0; k < 64; k += 2) {
            y0 = fmaf(sAct[wave][k],   sW[L][k][lane],   y0);
            y1 = fmaf(sAct[wave][k+1], sW[L][k+1][lane], y1);
        }
        __syncthreads();
        xv = y0 + y1;
    }
    {
        float ss = xv * xv;
        #pragma unroll
        for (int o = 1; o < 64; o <<= 1) ss += __shfl_xor(ss, o);
        sAct[wave][lane] = fmaxf(xv / (sqrtf(ss) * 0.125f + 1e-8f), 0.f);
    }
    // out projection: 8 chunks of 64 channels, weights staged into sW[0]
    auto& sWo = sW[0];
    float res[8];
    for (int qq = 0; qq < 8; ++qq) {
        __syncthreads();
        for (int idx = tid; idx < 4096; idx += 256)
            ((float*)sWo)[idx] = ow[(size_t)(idx >> 6)*512 + qq*64 + (idx & 63)];
        __syncthreads();
        float y0 = ob[qq*64 + lane], y1 = 0.f, y2 = 0.f, y3 = 0.f;
        #pragma unroll
        for (int k = 0; k < 64; k += 4) {
            y0 = fmaf(sAct[wave][k],   sWo[k  ][lane], y0);
            y1 = fmaf(sAct[wave][k+1], sWo[k+1][lane], y1);
            y2 = fmaf(sAct[wave][k+2], sWo[k+2][lane], y2);
            y3 = fmaf(sAct[wave][k+3], sWo[k+3][lane], y3);
        }
        res[qq] = (y0+y1+y2+y3) * dec;
    }
    #pragma unroll
    for (int qq = 0; qq < 8; ++qq)
        a_buf[(size_t)(qq*64 + lane)*NF + e] = res[qq];
}

// FFT of each kernel column -> scrambled-order spectrum.  512 threads.
__global__ __launch_bounds__(512, 4) void afft_kernel(
    const float* __restrict__ a_buf, const float2* __restrict__ tw,
    float2* __restrict__ Afft)
{
    __shared__ __align__(16) float2 Z[NF];   // 64 KB
    int cc = blockIdx.x, tid = threadIdx.x;
    const float* col = a_buf + (size_t)cc * NF;
    // A1: fused load + fwd8<1024,10>
    #pragma unroll
    for (int q = 0; q < 2; ++q) {
        int i = tid + q*512;
        float2 v0 = make_float2(col[i       ], 0.f);
        float2 v1 = make_float2(col[i + 1024], 0.f);
        float2 v2 = make_float2(col[i + 2048], 0.f);
        float2 v3 = make_float2(col[i + 3072], 0.f);
        float2 v4 = make_float2(col[i + 4096], 0.f);
        float2 v5 = make_float2(col[i + 5120], 0.f);
        float2 v6 = make_float2(col[i + 6144], 0.f);
        float2 v7 = make_float2(col[i + 7168], 0.f);
        dif8_core(v0,v1,v2,v3,v4,v5,v6,v7);
        int ts = i;
        Z[phys(i        )] = v0;
        Z[phys(i + 4096)] = cmul(v1, tw[ts*4]);
        Z[phys(i + 2048)] = cmul(v2, tw[ts*2]);
        Z[phys(i + 6144)] = cmul(v3, tw[ts*6]);
        Z[phys(i + 1024)] = cmul(v4, tw[ts  ]);
        Z[phys(i + 5120)] = cmul(v5, tw[ts*5]);
        Z[phys(i + 3072)] = cmul(v6, tw[ts*3]);
        Z[phys(i + 7168)] = cmul(v7, tw[ts*7]);
    }
    __syncthreads();
    fwd8_lds<128, 7>(Z, tw, tid);  __syncthreads();
    fwd8_lds<16,  4>(Z, tw, tid);  __syncthreads();
    // A4: fused fwd8<2,1> + fwd2 + store (register chunk of 16)
    {
        int c = tid, sw4 = c & 7;
        float4* Z4 = reinterpret_cast<float4*>(Z);
        float4* oc4 = reinterpret_cast<float4*>(Afft + (size_t)cc * NF);
        float2 z[16];
        #pragma unroll
        for (int j = 0; j < 8; ++j) {
            float4 wv = Z4[c*8 + (j ^ sw4)];
            z[2*j]   = make_float2(wv.x, wv.y);
            z[2*j+1] = make_float2(wv.z, wv.w);
        }
        dif8_core(z[0],z[2],z[4],z[6],z[8],z[10],z[12],z[14]);
        dif8_core(z[1],z[3],z[5],z[7],z[9],z[11],z[13],z[15]);
        // E_k: 0:z0 1:z8 2:z4 3:z12 4:z2 5:z10 6:z6 7:z14; O_k same +1
        #define A4K(k, ZE, ZO, WR, WI) { \
            float2 w = make_float2((WR)*(ZO).x - (WI)*(ZO).y, (WR)*(ZO).y + (WI)*(ZO).x); \
            float2 pp = cadd(ZE, w), rr = csub(ZE, w); \
            oc4[c*8 + (k)] = make_float4(pp.x, pp.y, rr.x, rr.y); }
        { float2 pp = cadd(z[0], z[1]), rr = csub(z[0], z[1]);
          oc4[c*8 + 0] = make_float4(pp.x, pp.y, rr.x, rr.y); }
        A4K(1, z[8],  z[9],   C16_1, -S16_1)
        A4K(2, z[4],  z[5],   C16_2, -C16_2)
        A4K(3, z[12], z[13],  S16_1, -C16_1)
        { float2 w = mnegi(z[3]);
          float2 pp = cadd(z[2], w), rr = csub(z[2], w);
          oc4[c*8 + 4] = make_float4(pp.x, pp.y, rr.x, rr.y); }
        A4K(5, z[10], z[11], -S16_1, -C16_1)
        A4K(6, z[6],  z[7],  -C16_2, -C16_2)
        A4K(7, z[14], z[15], -C16_1, -S16_1)
        #undef A4K
    }
}

// main conv: z = x[2bp] + i*x[2bp+1] -> FFT -> *A -> IFFT.  512 threads, 7 phases.
__global__ __launch_bounds__(512, 4) void conv_kernel(
    const float* __restrict__ x, const float2* __restrict__ tw,
    const float2* __restrict__ Afft, float* __restrict__ out)
{
    __shared__ __align__(16) float2 Z[NF];   // 64 KB -> 2 blocks/CU, 4 waves/SIMD
    int blk = blockIdx.x;
    int c8 = blk & 7, r = blk >> 3;
    int d  = ((c8 & 1) << 5) | (r & 31);
    int h  = (((r >> 5) & 3) << 1) | ((c8 >> 1) & 1);
    int bp = (((r >> 7) & 1) << 1) | ((c8 >> 2) & 1);
    int tid = threadIdx.x;
    size_t base0 = ((size_t)((bp*2 + 0)*8 + h) * 4096) * 64 + d;
    size_t base1 = ((size_t)((bp*2 + 1)*8 + h) * 4096) * 64 + d;

    // P1: fused global load + fwd8<1024,10> (upper half of input is zero)
    #pragma unroll
    for (int q = 0; q < 2; ++q) {
        int i = tid + q*512;
        float2 v0 = make_float2(x[base0 + (size_t)(i       )*64], x[base1 + (size_t)(i       )*64]);
        float2 v1 = make_float2(x[base0 + (size_t)(i + 1024)*64], x[base1 + (size_t)(i + 1024)*64]);
        float2 v2 = make_float2(x[base0 + (size_t)(i + 2048)*64], x[base1 + (size_t)(i + 2048)*64]);
        float2 v3 = make_float2(x[base0 + (size_t)(i + 3072)*64], x[base1 + (size_t)(i + 3072)*64]);
        // stage 1 with v4..v7 == 0:
        float2 v4 = v0;
        float2 v5 = mw81(v1);
        float2 v6 = mnegi(v2);
        float2 v7 = mw83(v3);
        float2 t;
        // stage 2
        t = csub(v0, v2); v0 = cadd(v0, v2); v2 = t;
        t = csub(v1, v3); v1 = cadd(v1, v3); v3 = mnegi(t);
        t = csub(v4, v6); v4 = cadd(v4, v6); v6 = t;
        t = csub(v5, v7); v5 = cadd(v5, v7); v7 = mnegi(t);
        // stage 3
        t = csub(v0, v1); v0 = cadd(v0, v1); v1 = t;
        t = csub(v2, v3); v2 = cadd(v2, v3); v3 = t;
        t = csub(v4, v5); v4 = cadd(v4, v5); v5 = t;
        t = csub(v6, v7); v6 = cadd(v6, v7); v7 = t;
        int ts = i;
        Z[phys(i        )] = v0;
        Z[phys(i + 4096)] = cmul(v1, tw[ts*4]);
        Z[phys(i + 2048)] = cmul(v2, tw[ts*2]);
        Z[phys(i + 6144)] = cmul(v3, tw[ts*6]);
        Z[phys(i + 1024)] = cmul(v4, tw[ts  ]);
        Z[phys(i + 5120)] = cmul(v5, tw[ts*5]);
        Z[phys(i + 3072)] = cmul(v6, tw[ts*3]);
        Z[phys(i + 7168)] = cmul(v7, tw[ts*7]);
    }
    __syncthreads();
    fwd8_lds<128, 7>(Z, tw, tid);  __syncthreads();
    fwd8_lds<16,  4>(Z, tw, tid);  __syncthreads();

    // P4: fused fwd8<2,1> + fwd2 + (*A) + inv2 + inv8<2,1> — register chunk of 16
    {
        int c = tid, sw4 = c & 7;
        float4* Z4 = reinterpret_cast<float4*>(Z);
        const float4* A4 = reinterpret_cast<const float4*>(Afft + (size_t)(h*64 + d)*NF);
        float2 z[16];
        #pragma unroll
        for (int j = 0; j < 8; ++j) {
            float4 wv = Z4[c*8 + (j ^ sw4)];
            z[2*j]   = make_float2(wv.x, wv.y);
            z[2*j+1] = make_float2(wv.z, wv.w);
        }
        dif8_core(z[0],z[2],z[4],z[6],z[8],z[10],z[12],z[14]);
        dif8_core(z[1],z[3],z[5],z[7],z[9],z[11],z[13],z[15]);
        // pair k: E_k reg / O_k reg: 0:z0/z1 1:z8/z9 2:z4/z5 3:z12/z13 4:z2/z3 5:z10/z11 6:z6/z7 7:z14/z15
        #define P4K(k, ZE, ZO, WR, WI) { \
            float2 w = make_float2((WR)*(ZO).x - (WI)*(ZO).y, (WR)*(ZO).y + (WI)*(ZO).x); \
            float2 pp = cadd(ZE, w), rr = csub(ZE, w); \
            float4 av = A4[c*8 + (k)]; \
            pp = cmul(pp, make_float2(av.x, av.y)); \
            rr = cmul(rr, make_float2(av.z, av.w)); \
            ZE = cadd(pp, rr); \
            ZO = csub(pp, rr); }
        { float2 pp = cadd(z[0], z[1]), rr = csub(z[0], z[1]);
          float4 av = A4[c*8 + 0];
          pp = cmul(pp, make_float2(av.x, av.y));
          rr = cmul(rr, make_float2(av.z, av.w));
          z[0] = cadd(pp, rr); z[1] = csub(pp, rr); }
        P4K(1, z[8],  z[9],   C16_1, -S16_1)
        P4K(2, z[4],  z[5],   C16_2, -C16_2)
        P4K(3, z[12], z[13],  S16_1, -C16_1)
        { float2 w = mnegi(z[3]);
          float2 pp = cadd(z[2], w), rr = csub(z[2], w);
          float4 av = A4[c*8 + 4];
          pp = cmul(pp, make_float2(av.x, av.y));
          rr = cmul(rr, make_float2(av.z, av.w));
          z[2] = cadd(pp, rr); z[3] = csub(pp, rr); }
        P4K(5, z[10], z[11], -S16_1, -C16_1)
        P4K(6, z[6],  z[7],  -C16_2, -C16_2)
        P4K(7, z[14], z[15], -C16_1, -S16_1)
        #undef P4K
        // conj twiddles on odd legs for the inverse radix-8 (i=1 butterfly)
        z[3]  = mposi(z[3]);                                     // *conj(W16^4)
        z[5]  = cmul(z[5],  make_float2( C16_2,  C16_2));        // *conj(W16^2)
        z[7]  = cmul(z[7],  make_float2(-C16_2,  C16_2));        // *conj(W16^6)
        z[9]  = cmul(z[9],  make_float2( C16_1,  S16_1));        // *conj(W16^1)
        z[11] = cmul(z[11], make_float2(-S16_1,  C16_1));        // *conj(W16^5)
        z[13] = cmul(z[13], make_float2( S16_1,  C16_1));        // *conj(W16^3)
        z[15] = cmul(z[15], make_float2(-C16_1,  S16_1));        // *conj(W16^7)
        dit8_core(z[0],z[2],z[4],z[6],z[8],z[10],z[12],z[14]);
        dit8_core(z[1],z[3],z[5],z[7],z[9],z[11],z[13],z[15]);
        #pragma unroll
        for (int j = 0; j < 8; ++j)
            Z4[c*8 + (j ^ sw4)] = make_float4(z[2*j].x, z[2*j].y, z[2*j+1].x, z[2*j+1].y);
    }
    __syncthreads();
    inv8_lds<16,  4>(Z, tw, tid);  __syncthreads();
    inv8_lds<128, 7>(Z, tw, tid);  __syncthreads();

    // P7: fused inv8<1024,10> + store (only legs 0..3 are kept)
    const float sc = 1.0f/8192.0f;
    #pragma unroll
    for (int q = 0; q < 2; ++q) {
        int i = tid + q*512;
        int ts = i;
        float2 v0 = Z[phys(i        )];
        float2 v1 = cmulc(Z[phys(i + 4096)], tw[ts*4]);
        float2 v2 = cmulc(Z[phys(i + 2048)], tw[ts*2]);
        float2 v3 = cmulc(Z[phys(i + 6144)], tw[ts*6]);
        float2 v4 = cmulc(Z[phys(i + 1024)], tw[ts  ]);
        float2 v5 = cmulc(Z[phys(i + 5120)], tw[ts*5]);
        float2 v6 = cmulc(Z[phys(i + 3072)], tw[ts*3]);
        float2 v7 = cmulc(Z[phys(i + 7168)], tw[ts*7]);
        float2 t;
        t = csub(v0, v1); v0 = cadd(v0, v1); v1 = t;
        t = csub(v2, v3); v2 = cadd(v2, v3); v3 = t;
        t = csub(v4, v5); v4 = cadd(v4, v5); v5 = t;
        t = csub(v6, v7); v6 = cadd(v6, v7); v7 = t;
        t = v2;        v2 = csub(v0, t); v0 = cadd(v0, t);
        t = mposi(v3); v3 = csub(v1, t); v1 = cadd(v1, t);
        t = v6;        v6 = csub(v4, t); v4 = cadd(v4, t);
        t = mposi(v7); v7 = csub(v5, t); v5 = cadd(v5, t);
        // stage-1 inverse: keep only the "+" outputs (legs 0..3)
        v0 = cadd(v0, v4);
        v1 = cadd(v1, mw81c(v5));
        v2 = cadd(v2, mposi(v6));
        v3 = cadd(v3, mw83c(v7));
        out[base0 + (size_t)(i       )*64] = v0.x * sc;
        out[base1 + (size_t)(i       )*64] = v0.y * sc;
        out[base0 + (size_t)(i + 1024)*64] = v1.x * sc;
        out[base1 + (size_t)(i + 1024)*64] = v1.y * sc;
        out[base0 + (size_t)(i + 2048)*64] = v2.x * sc;
        out[base1 + (size_t)(i + 2048)*64] = v2.y * sc;
        out[base0 + (size_t)(i + 3072)*64] = v3.x * sc;
        out[base1 + (size_t)(i + 3072)*64] = v3.y * sc;
    }
}

extern "C" void kernel_launch(void* const* d_in, const int* in_sizes, int n_in,
                              void* d_out, int out_size, void* d_ws, size_t ws_size,
                              hipStream_t stream) {
    const float* x   = (const float*)d_in[0];
    const float* pw  = (const float*)d_in[1];
    const float* pb  = (const float*)d_in[2];
    const float* lws = (const float*)d_in[3];
    const float* lbs = (const float*)d_in[4];
    const float* ow  = (const float*)d_in[5];
    const float* ob  = (const float*)d_in[6];
    float* out = (float*)d_out;
    char* ws = (char*)d_ws;
    // ws layout: [0,64K) twiddles | [64K, 64K+16M) a_buf | [.., +32M) Afft  (~48.1 MB total)
    float2* tw    = (float2*)ws;
    float*  a_buf = (float*)(ws + 65536);
    float2* Afft  = (float2*)(ws + 65536 + (size_t)512*NF*4);

    twiddle_kernel<<<32, 256, 0, stream>>>(tw);
    rpe_kernel<<<2048, 256, 0, stream>>>(pw, pb, lws, lbs, ow, ob, a_buf);
    afft_kernel<<<512, 512, 0, stream>>>(a_buf, tw, Afft);
    conv_kernel<<<2048, 512, 0, stream>>>(x, tw, Afft, out);
}

// Round 3
// 543.150 us; speedup vs baseline: 1.0798x; 1.0798x over previous
//
#include <hip/hip_runtime.h>
#include <math.h>

#define NF 8192

// ---------- complex helpers ----------
__device__ __forceinline__ int phys(int e) { return e ^ (((e >> 4) & 7) << 1); }

__device__ __forceinline__ float2 cmul(float2 a, float2 b) {
    return make_float2(a.x*b.x - a.y*b.y, a.x*b.y + a.y*b.x);
}
__device__ __forceinline__ float2 cmulc(float2 a, float2 b) { // a * conj(b)
    return make_float2(a.x*b.x + a.y*b.y, a.y*b.x - a.x*b.y);
}
__device__ __forceinline__ float2 cadd(float2 a, float2 b){ return make_float2(a.x+b.x, a.y+b.y); }
__device__ __forceinline__ float2 csub(float2 a, float2 b){ return make_float2(a.x-b.x, a.y-b.y); }
__device__ __forceinline__ float2 mnegi(float2 a){ return make_float2(a.y, -a.x); }   // * (-i)
__device__ __forceinline__ float2 mposi(float2 a){ return make_float2(-a.y, a.x); }   // * (+i)
#define RSQ2 0.70710678118654752f
__device__ __forceinline__ float2 mw81 (float2 a){ return make_float2( RSQ2*(a.x+a.y),  RSQ2*(a.y-a.x)); } // * e^{-i pi/4}
__device__ __forceinline__ float2 mw83 (float2 a){ return make_float2( RSQ2*(a.y-a.x), -RSQ2*(a.x+a.y)); } // * e^{-3i pi/4}
__device__ __forceinline__ float2 mw81c(float2 a){ return make_float2( RSQ2*(a.x-a.y),  RSQ2*(a.x+a.y)); } // * e^{+i pi/4}
__device__ __forceinline__ float2 mw83c(float2 a){ return make_float2(-RSQ2*(a.x+a.y),  RSQ2*(a.x-a.y)); } // * e^{+3i pi/4}

// w16 constants
#define C16_1 0.92387953251128674f
#define S16_1 0.38268343236508978f
#define C16_2 0.70710678118654752f

// base twiddle exp(-2*pi*i*ts/8192) via HW transcendentals (input in revolutions, |arg|<1)
__device__ __forceinline__ float2 twbase(int ts) {
    float fa = (float)ts * (1.0f/8192.0f);
    return make_float2(__builtin_amdgcn_cosf(fa), -__builtin_amdgcn_sinf(fa));
}

// DIF radix-8 core. After: y0=v0 y1=v4 y2=v2 y3=v6 y4=v1 y5=v5 y6=v3 y7=v7
__device__ __forceinline__ void dif8_core(float2& v0, float2& v1, float2& v2, float2& v3,
                                          float2& v4, float2& v5, float2& v6, float2& v7) {
    float2 t;
    t = csub(v0, v4); v0 = cadd(v0, v4); v4 = t;
    t = csub(v1, v5); v1 = cadd(v1, v5); v5 = mw81(t);
    t = csub(v2, v6); v2 = cadd(v2, v6); v6 = mnegi(t);
    t = csub(v3, v7); v3 = cadd(v3, v7); v7 = mw83(t);
    t = csub(v0, v2); v0 = cadd(v0, v2); v2 = t;
    t = csub(v1, v3); v1 = cadd(v1, v3); v3 = mnegi(t);
    t = csub(v4, v6); v4 = cadd(v4, v6); v6 = t;
    t = csub(v5, v7); v5 = cadd(v5, v7); v7 = mnegi(t);
    t = csub(v0, v1); v0 = cadd(v0, v1); v1 = t;
    t = csub(v2, v3); v2 = cadd(v2, v3); v3 = t;
    t = csub(v4, v5); v4 = cadd(v4, v5); v5 = t;
    t = csub(v6, v7); v6 = cadd(v6, v7); v7 = t;
}

// DIT radix-8 core. Inputs v0=y0 v1=y4*c4 v2=y2*c2 v3=y6*c6 v4=y1*c1 v5=y5*c5 v6=y3*c3 v7=y7*c7
__device__ __forceinline__ void dit8_core(float2& v0, float2& v1, float2& v2, float2& v3,
                                          float2& v4, float2& v5, float2& v6, float2& v7) {
    float2 t;
    t = csub(v0, v1); v0 = cadd(v0, v1); v1 = t;
    t = csub(v2, v3); v2 = cadd(v2, v3); v3 = t;
    t = csub(v4, v5); v4 = cadd(v4, v5); v5 = t;
    t = csub(v6, v7); v6 = cadd(v6, v7); v7 = t;
    t = v2;        v2 = csub(v0, t); v0 = cadd(v0, t);
    t = mposi(v3); v3 = csub(v1, t); v1 = cadd(v1, t);
    t = v6;        v6 = csub(v4, t); v4 = cadd(v4, t);
    t = mposi(v7); v7 = csub(v5, t); v5 = cadd(v5, t);
    t = v4;        v4 = csub(v0, t); v0 = cadd(v0, t);
    t = mw81c(v5); v5 = csub(v1, t); v1 = cadd(v1, t);
    t = mposi(v6); v6 = csub(v2, t); v2 = cadd(v2, t);
    t = mw83c(v7); v7 = csub(v3, t); v3 = cadd(v3, t);
}

// compute w^1..w^7 from base ts
#define TW_POWERS(ts) \
    float2 w1 = twbase(ts); \
    float2 w2 = cmul(w1, w1); \
    float2 w3 = cmul(w2, w1); \
    float2 w4 = cmul(w2, w2); \
    float2 w5 = cmul(w3, w2); \
    float2 w6 = cmul(w3, w3); \
    float2 w7 = cmul(w4, w3);

// ---------- radix-8 LDS passes (512 threads) ----------
template<int M, int LM>
__device__ __forceinline__ void fwd8_lds(float2* Z, int tid) {
    #pragma unroll
    for (int q = 0; q < 2; ++q) {
        int beta = tid + q*512;
        int i    = beta & (M-1);
        int base = ((beta >> LM) << (LM+3)) + i;
        float2 v0 = Z[phys(base        )];
        float2 v1 = Z[phys(base + 1*M)];
        float2 v2 = Z[phys(base + 2*M)];
        float2 v3 = Z[phys(base + 3*M)];
        float2 v4 = Z[phys(base + 4*M)];
        float2 v5 = Z[phys(base + 5*M)];
        float2 v6 = Z[phys(base + 6*M)];
        float2 v7 = Z[phys(base + 7*M)];
        dif8_core(v0,v1,v2,v3,v4,v5,v6,v7);
        TW_POWERS((NF >> (LM+3)) * i)
        Z[phys(base        )] = v0;
        Z[phys(base + 4*M)] = cmul(v1, w4);
        Z[phys(base + 2*M)] = cmul(v2, w2);
        Z[phys(base + 6*M)] = cmul(v3, w6);
        Z[phys(base + 1*M)] = cmul(v4, w1);
        Z[phys(base + 5*M)] = cmul(v5, w5);
        Z[phys(base + 3*M)] = cmul(v6, w3);
        Z[phys(base + 7*M)] = cmul(v7, w7);
    }
}

template<int M, int LM>
__device__ __forceinline__ void inv8_lds(float2* Z, int tid) {
    #pragma unroll
    for (int q = 0; q < 2; ++q) {
        int beta = tid + q*512;
        int i    = beta & (M-1);
        int base = ((beta >> LM) << (LM+3)) + i;
        TW_POWERS((NF >> (LM+3)) * i)
        float2 v0 = Z[phys(base        )];
        float2 v1 = cmulc(Z[phys(base + 4*M)], w4);
        float2 v2 = cmulc(Z[phys(base + 2*M)], w2);
        float2 v3 = cmulc(Z[phys(base + 6*M)], w6);
        float2 v4 = cmulc(Z[phys(base + 1*M)], w1);
        float2 v5 = cmulc(Z[phys(base + 5*M)], w5);
        float2 v6 = cmulc(Z[phys(base + 3*M)], w3);
        float2 v7 = cmulc(Z[phys(base + 7*M)], w7);
        dit8_core(v0,v1,v2,v3,v4,v5,v6,v7);
        Z[phys(base        )] = v0;
        Z[phys(base + 1*M)] = v1;
        Z[phys(base + 2*M)] = v2;
        Z[phys(base + 3*M)] = v3;
        Z[phys(base + 4*M)] = v4;
        Z[phys(base + 5*M)] = v5;
        Z[phys(base + 6*M)] = v6;
        Z[phys(base + 7*M)] = v7;
    }
}

// ---------- kernels ----------

// Position-MLP: a[c][e] = decay(e) * rpe(offset(e))[c].  256 blocks x 512 thr, 32 pos/block.
__global__ __launch_bounds__(512) void rpe_kernel(
    const float* __restrict__ pw,  const float* __restrict__ pb,
    const float* __restrict__ lws, const float* __restrict__ lbs,
    const float* __restrict__ ow,  const float* __restrict__ ob,
    float* __restrict__ a_buf)
{
    __shared__ float sW[3][64][64];     // 48 KB
    __shared__ float sWo[64][64];       // 16 KB
    __shared__ float sB[3][64];
    __shared__ float sPW[64], sPB[64];
    __shared__ float sAct[8][4][64];    // 8 KB (wave-private rows)
    int tid = threadIdx.x;
    for (int idx = tid; idx < 3*64*64; idx += 512) ((float*)sW)[idx] = lws[idx];
    if (tid < 192) ((float*)sB)[tid] = lbs[tid];
    if (tid < 64) { sPW[tid] = pw[tid]; sPB[tid] = pb[tid]; }
    __syncthreads();

    int wv = tid >> 6, lane = tid & 63;
    int e0 = blockIdx.x * 32 + wv * 4;
    float dec[4];
    #pragma unroll
    for (int s = 0; s < 4; ++s) {
        int e = e0 + s;
        float p = (e == 4096) ? 0.f : ((e < 4096) ? (float)e : (float)(e - 8192));
        int m = (e < 4096) ? e : (8192 - e);
        if (e == 4096) m = 0;
        dec[s] = exp2f(-0.0014434309482562475f * (float)m);   // log2(0.999)

        float xv = fmaf(p, sPW[lane], sPB[lane]);
        #pragma unroll
        for (int L = 0; L < 3; ++L) {
            float ss = xv * xv;
            #pragma unroll
            for (int o = 1; o < 64; o <<= 1) ss += __shfl_xor(ss, o);
            sAct[wv][s][lane] = fmaxf(xv / (sqrtf(ss) * 0.125f + 1e-8f), 0.f);
            // wave-private LDS RAW: lgkmcnt ordering is enough, no barrier
            float y = sB[L][lane];
            const float4* av = reinterpret_cast<const float4*>(sAct[wv][s]);
            #pragma unroll
            for (int k = 0; k < 16; ++k) {
                float4 a4 = av[k];
                y = fmaf(a4.x, sW[L][4*k  ][lane], y);
                y = fmaf(a4.y, sW[L][4*k+1][lane], y);
                y = fmaf(a4.z, sW[L][4*k+2][lane], y);
                y = fmaf(a4.w, sW[L][4*k+3][lane], y);
            }
            xv = y;
        }
        float ss = xv * xv;
        #pragma unroll
        for (int o = 1; o < 64; o <<= 1) ss += __shfl_xor(ss, o);
        sAct[wv][s][lane] = fmaxf(xv / (sqrtf(ss) * 0.125f + 1e-8f), 0.f);
    }
    // out projection: 8 chunks of 64 channels, weights staged into sWo
    for (int qq = 0; qq < 8; ++qq) {
        __syncthreads();
        for (int idx = tid; idx < 4096; idx += 512)
            ((float*)sWo)[idx] = ow[(size_t)(idx >> 6)*512 + qq*64 + (idx & 63)];
        __syncthreads();
        #pragma unroll
        for (int s = 0; s < 4; ++s) {
            float y = ob[qq*64 + lane];
            const float4* av = reinterpret_cast<const float4*>(sAct[wv][s]);
            #pragma unroll
            for (int k = 0; k < 16; ++k) {
                float4 a4 = av[k];
                y = fmaf(a4.x, sWo[4*k  ][lane], y);
                y = fmaf(a4.y, sWo[4*k+1][lane], y);
                y = fmaf(a4.z, sWo[4*k+2][lane], y);
                y = fmaf(a4.w, sWo[4*k+3][lane], y);
            }
            a_buf[(size_t)(qq*64 + lane)*NF + (e0 + s)] = y * dec[s];
        }
    }
}

// FFT of each kernel column -> scrambled-order spectrum, stored transposed [k][c].
__global__ __launch_bounds__(512, 4) void afft_kernel(
    const float* __restrict__ a_buf, float2* __restrict__ Afft)
{
    __shared__ __align__(16) float2 Z[NF];   // 64 KB
    int cc = blockIdx.x, tid = threadIdx.x;
    const float* col = a_buf + (size_t)cc * NF;
    // A1: fused load + fwd8<1024,10>
    #pragma unroll
    for (int q = 0; q < 2; ++q) {
        int i = tid + q*512;
        float2 v0 = make_float2(col[i       ], 0.f);
        float2 v1 = make_float2(col[i + 1024], 0.f);
        float2 v2 = make_float2(col[i + 2048], 0.f);
        float2 v3 = make_float2(col[i + 3072], 0.f);
        float2 v4 = make_float2(col[i + 4096], 0.f);
        float2 v5 = make_float2(col[i + 5120], 0.f);
        float2 v6 = make_float2(col[i + 6144], 0.f);
        float2 v7 = make_float2(col[i + 7168], 0.f);
        dif8_core(v0,v1,v2,v3,v4,v5,v6,v7);
        TW_POWERS(i)
        Z[phys(i        )] = v0;
        Z[phys(i + 4096)] = cmul(v1, w4);
        Z[phys(i + 2048)] = cmul(v2, w2);
        Z[phys(i + 6144)] = cmul(v3, w6);
        Z[phys(i + 1024)] = cmul(v4, w1);
        Z[phys(i + 5120)] = cmul(v5, w5);
        Z[phys(i + 3072)] = cmul(v6, w3);
        Z[phys(i + 7168)] = cmul(v7, w7);
    }
    __syncthreads();
    fwd8_lds<128, 7>(Z, tid);  __syncthreads();
    fwd8_lds<16,  4>(Z, tid);  __syncthreads();
    // A4: fused fwd8<2,1> + fwd2 + transposed store
    {
        int c = tid, sw4 = c & 7;
        float4* Z4 = reinterpret_cast<float4*>(Z);
        float4* oc4 = reinterpret_cast<float4*>(Afft + (size_t)cc * NF);
        float2 z[16];
        #pragma unroll
        for (int j = 0; j < 8; ++j) {
            float4 wv = Z4[c*8 + (j ^ sw4)];
            z[2*j]   = make_float2(wv.x, wv.y);
            z[2*j+1] = make_float2(wv.z, wv.w);
        }
        dif8_core(z[0],z[2],z[4],z[6],z[8],z[10],z[12],z[14]);
        dif8_core(z[1],z[3],z[5],z[7],z[9],z[11],z[13],z[15]);
        #define A4K(k, ZE, ZO, WR, WI) { \
            float2 w = make_float2((WR)*(ZO).x - (WI)*(ZO).y, (WR)*(ZO).y + (WI)*(ZO).x); \
            float2 pp = cadd(ZE, w), rr = csub(ZE, w); \
            oc4[(k)*512 + c] = make_float4(pp.x, pp.y, rr.x, rr.y); }
        { float2 pp = cadd(z[0], z[1]), rr = csub(z[0], z[1]);
          oc4[0*512 + c] = make_float4(pp.x, pp.y, rr.x, rr.y); }
        A4K(1, z[8],  z[9],   C16_1, -S16_1)
        A4K(2, z[4],  z[5],   C16_2, -C16_2)
        A4K(3, z[12], z[13],  S16_1, -C16_1)
        { float2 w = mnegi(z[3]);
          float2 pp = cadd(z[2], w), rr = csub(z[2], w);
          oc4[4*512 + c] = make_float4(pp.x, pp.y, rr.x, rr.y); }
        A4K(5, z[10], z[11], -S16_1, -C16_1)
        A4K(6, z[6],  z[7],  -C16_2, -C16_2)
        A4K(7, z[14], z[15], -C16_1, -S16_1)
        #undef A4K
    }
}

// main conv: z = x[2bp] + i*x[2bp+1] -> FFT -> *A -> IFFT.  512 threads, 7 phases.
__global__ __launch_bounds__(512, 4) void conv_kernel(
    const float* __restrict__ x, const float2* __restrict__ Afft,
    float* __restrict__ out)
{
    __shared__ __align__(16) float2 Z[NF];   // 64 KB -> 2 blocks/CU
    int blk = blockIdx.x;
    int c8 = blk & 7, r = blk >> 3;
    int d  = ((c8 & 1) << 5) | (r & 31);
    int h  = (((r >> 5) & 3) << 1) | ((c8 >> 1) & 1);
    int bp = (((r >> 7) & 1) << 1) | ((c8 >> 2) & 1);
    int tid = threadIdx.x;
    size_t base0 = ((size_t)((bp*2 + 0)*8 + h) * 4096) * 64 + d;
    size_t base1 = ((size_t)((bp*2 + 1)*8 + h) * 4096) * 64 + d;

    // P1: fused global load + fwd8<1024,10> (upper half of input is zero)
    #pragma unroll
    for (int q = 0; q < 2; ++q) {
        int i = tid + q*512;
        float2 v0 = make_float2(x[base0 + (size_t)(i       )*64], x[base1 + (size_t)(i       )*64]);
        float2 v1 = make_float2(x[base0 + (size_t)(i + 1024)*64], x[base1 + (size_t)(i + 1024)*64]);
        float2 v2 = make_float2(x[base0 + (size_t)(i + 2048)*64], x[base1 + (size_t)(i + 2048)*64]);
        float2 v3 = make_float2(x[base0 + (size_t)(i + 3072)*64], x[base1 + (size_t)(i + 3072)*64]);
        float2 v4 = v0;
        float2 v5 = mw81(v1);
        float2 v6 = mnegi(v2);
        float2 v7 = mw83(v3);
        float2 t;
        t = csub(v0, v2); v0 = cadd(v0, v2); v2 = t;
        t = csub(v1, v3); v1 = cadd(v1, v3); v3 = mnegi(t);
        t = csub(v4, v6); v4 = cadd(v4, v6); v6 = t;
        t = csub(v5, v7); v5 = cadd(v5, v7); v7 = mnegi(t);
        t = csub(v0, v1); v0 = cadd(v0, v1); v1 = t;
        t = csub(v2, v3); v2 = cadd(v2, v3); v3 = t;
        t = csub(v4, v5); v4 = cadd(v4, v5); v5 = t;
        t = csub(v6, v7); v6 = cadd(v6, v7); v7 = t;
        TW_POWERS(i)
        Z[phys(i        )] = v0;
        Z[phys(i + 4096)] = cmul(v1, w4);
        Z[phys(i + 2048)] = cmul(v2, w2);
        Z[phys(i + 6144)] = cmul(v3, w6);
        Z[phys(i + 1024)] = cmul(v4, w1);
        Z[phys(i + 5120)] = cmul(v5, w5);
        Z[phys(i + 3072)] = cmul(v6, w3);
        Z[phys(i + 7168)] = cmul(v7, w7);
    }
    __syncthreads();
    fwd8_lds<128, 7>(Z, tid);  __syncthreads();
    fwd8_lds<16,  4>(Z, tid);  __syncthreads();

    // P4: fused fwd8<2,1> + fwd2 + (*A) + inv2 + inv8<2,1> — register chunk of 16
    {
        int c = tid, sw4 = c & 7;
        float4* Z4 = reinterpret_cast<float4*>(Z);
        const float4* A4 = reinterpret_cast<const float4*>(Afft + (size_t)(h*64 + d)*NF);
        float2 z[16];
        #pragma unroll
        for (int j = 0; j < 8; ++j) {
            float4 wv = Z4[c*8 + (j ^ sw4)];
            z[2*j]   = make_float2(wv.x, wv.y);
            z[2*j+1] = make_float2(wv.z, wv.w);
        }
        dif8_core(z[0],z[2],z[4],z[6],z[8],z[10],z[12],z[14]);
        dif8_core(z[1],z[3],z[5],z[7],z[9],z[11],z[13],z[15]);
        #define P4K(k, ZE, ZO, WR, WI) { \
            float2 w = make_float2((WR)*(ZO).x - (WI)*(ZO).y, (WR)*(ZO).y + (WI)*(ZO).x); \
            float2 pp = cadd(ZE, w), rr = csub(ZE, w); \
            float4 av = A4[(k)*512 + c]; \
            pp = cmul(pp, make_float2(av.x, av.y)); \
            rr = cmul(rr, make_float2(av.z, av.w)); \
            ZE = cadd(pp, rr); \
            ZO = csub(pp, rr); }
        { float2 pp = cadd(z[0], z[1]), rr = csub(z[0], z[1]);
          float4 av = A4[0*512 + c];
          pp = cmul(pp, make_float2(av.x, av.y));
          rr = cmul(rr, make_float2(av.z, av.w));
          z[0] = cadd(pp, rr); z[1] = csub(pp, rr); }
        P4K(1, z[8],  z[9],   C16_1, -S16_1)
        P4K(2, z[4],  z[5],   C16_2, -C16_2)
        P4K(3, z[12], z[13],  S16_1, -C16_1)
        { float2 w = mnegi(z[3]);
          float2 pp = cadd(z[2], w), rr = csub(z[2], w);
          float4 av = A4[4*512 + c];
          pp = cmul(pp, make_float2(av.x, av.y));
          rr = cmul(rr, make_float2(av.z, av.w));
          z[2] = cadd(pp, rr); z[3] = csub(pp, rr); }
        P4K(5, z[10], z[11], -S16_1, -C16_1)
        P4K(6, z[6],  z[7],  -C16_2, -C16_2)
        P4K(7, z[14], z[15], -C16_1, -S16_1)
        #undef P4K
        // conj twiddles on odd legs for the inverse radix-8 (i=1 butterfly)
        z[3]  = mposi(z[3]);
        z[5]  = cmul(z[5],  make_float2( C16_2,  C16_2));
        z[7]  = cmul(z[7],  make_float2(-C16_2,  C16_2));
        z[9]  = cmul(z[9],  make_float2( C16_1,  S16_1));
        z[11] = cmul(z[11], make_float2(-S16_1,  C16_1));
        z[13] = cmul(z[13], make_float2( S16_1,  C16_1));
        z[15] = cmul(z[15], make_float2(-C16_1,  S16_1));
        dit8_core(z[0],z[2],z[4],z[6],z[8],z[10],z[12],z[14]);
        dit8_core(z[1],z[3],z[5],z[7],z[9],z[11],z[13],z[15]);
        #pragma unroll
        for (int j = 0; j < 8; ++j)
            Z4[c*8 + (j ^ sw4)] = make_float4(z[2*j].x, z[2*j].y, z[2*j+1].x, z[2*j+1].y);
    }
    __syncthreads();
    inv8_lds<16,  4>(Z, tid);  __syncthreads();
    inv8_lds<128, 7>(Z, tid);  __syncthreads();

    // P7: fused inv8<1024,10> + store (only legs 0..3 are kept)
    const float sc = 1.0f/8192.0f;
    #pragma unroll
    for (int q = 0; q < 2; ++q) {
        int i = tid + q*512;
        TW_POWERS(i)
        float2 v0 = Z[phys(i        )];
        float2 v1 = cmulc(Z[phys(i + 4096)], w4);
        float2 v2 = cmulc(Z[phys(i + 2048)], w2);
        float2 v3 = cmulc(Z[phys(i + 6144)], w6);
        float2 v4 = cmulc(Z[phys(i + 1024)], w1);
        float2 v5 = cmulc(Z[phys(i + 5120)], w5);
        float2 v6 = cmulc(Z[phys(i + 3072)], w3);
        float2 v7 = cmulc(Z[phys(i + 7168)], w7);
        float2 t;
        t = csub(v0, v1); v0 = cadd(v0, v1); v1 = t;
        t = csub(v2, v3); v2 = cadd(v2, v3); v3 = t;
        t = csub(v4, v5); v4 = cadd(v4, v5); v5 = t;
        t = csub(v6, v7); v6 = cadd(v6, v7); v7 = t;
        t = v2;        v2 = csub(v0, t); v0 = cadd(v0, t);
        t = mposi(v3); v3 = csub(v1, t); v1 = cadd(v1, t);
        t = v6;        v6 = csub(v4, t); v4 = cadd(v4, t);
        t = mposi(v7); v7 = csub(v5, t); v5 = cadd(v5, t);
        v0 = cadd(v0, v4);
        v1 = cadd(v1, mw81c(v5));
        v2 = cadd(v2, mposi(v6));
        v3 = cadd(v3, mw83c(v7));
        out[base0 + (size_t)(i       )*64] = v0.x * sc;
        out[base1 + (size_t)(i       )*64] = v0.y * sc;
        out[base0 + (size_t)(i + 1024)*64] = v1.x * sc;
        out[base1 + (size_t)(i + 1024)*64] = v1.y * sc;
        out[base0 + (size_t)(i + 2048)*64] = v2.x * sc;
        out[base1 + (size_t)(i + 2048)*64] = v2.y * sc;
        out[base0 + (size_t)(i + 3072)*64] = v3.x * sc;
        out[base1 + (size_t)(i + 3072)*64] = v3.y * sc;
    }
}

extern "C" void kernel_launch(void* const* d_in, const int* in_sizes, int n_in,
                              void* d_out, int out_size, void* d_ws, size_t ws_size,
                              hipStream_t stream) {
    const float* x   = (const float*)d_in[0];
    const float* pw  = (const float*)d_in[1];
    const float* pb  = (const float*)d_in[2];
    const float* lws = (const float*)d_in[3];
    const float* lbs = (const float*)d_in[4];
    const float* ow  = (const float*)d_in[5];
    const float* ob  = (const float*)d_in[6];
    float* out = (float*)d_out;
    char* ws = (char*)d_ws;
    // ws layout: [0, 16M) a_buf | [16M, 48M) Afft
    float*  a_buf = (float*)ws;
    float2* Afft  = (float2*)(ws + (size_t)512*NF*4);

    rpe_kernel<<<256, 512, 0, stream>>>(pw, pb, lws, lbs, ow, ob, a_buf);
    afft_kernel<<<512, 512, 0, stream>>>(a_buf, Afft);
    conv_kernel<<<2048, 512, 0, stream>>>(x, Afft, out);
}